// Round 11
// baseline (188.620 us; speedup 1.0000x reference)
//
#include <hip/hip_runtime.h>
#include <hip/hip_bf16.h>
#include <cstddef>
#include <cstdint>

#define DIM   1024
#define NH    16
#define HD    64
#define BATCH 2
#define SEQ   2048
#define NROWS (BATCH * SEQ)   // 4096
#define QSCALE 0.1803368801111204f   // 0.125 * log2(e): softmax in exp2 domain

typedef __bf16 bfrag  __attribute__((ext_vector_type(8)));
typedef float  f32x4  __attribute__((ext_vector_type(4)));

#if __has_builtin(__builtin_amdgcn_exp2f)
#define EXP2F(x) __builtin_amdgcn_exp2f(x)
#else
#define EXP2F(x) exp2f(x)
#endif

__device__ __forceinline__ unsigned short f2bf(float f) {
  union { float f; uint32_t u; } v; v.f = f;
  uint32_t r = (v.u + 0x7FFF + ((v.u >> 16) & 1)) >> 16;
  return (unsigned short)r;
}

__device__ __forceinline__ void async_copy16(const unsigned short* g,
                                             unsigned short* l) {
  __builtin_amdgcn_global_load_lds(
      (const __attribute__((address_space(1))) unsigned int*)g,
      (__attribute__((address_space(3))) unsigned int*)l, 16, 0, 0);
}

// ---------------------------------------------------------------------------
// Prep (single launch): section 0 = x fp32->bf16; sections 1/2 = W_qkv /
// W_proj transpose-convert. Branch is block-uniform (on blockIdx).
// ---------------------------------------------------------------------------
__global__ __launch_bounds__(256) void cvt_all(
    const float* __restrict__ x, unsigned short* __restrict__ xb,
    const float* __restrict__ Wq, unsigned short* __restrict__ Wtq,
    const float* __restrict__ Wp, unsigned short* __restrict__ Wtp) {
  int bid = blockIdx.x;
  const int tid = threadIdx.x;
  if (bid < 4096) {                    // cvt_x: 1024 floats per block
    int i = (bid * 256 + tid) * 4;
    float4 v = *(const float4*)(x + i);
    ushort4 p = {f2bf(v.x), f2bf(v.y), f2bf(v.z), f2bf(v.w)};
    *(ushort4*)(xb + i) = p;
    return;
  }
  bid -= 4096;
  const float* src;
  unsigned short* dst;
  int R, C, bx, by;
  if (bid < 3072) {                    // W_qkv [1024][3072] -> [3072][1024]
    src = Wq; dst = Wtq; R = DIM; C = 3072;
    bx = bid % 96; by = bid / 96;
  } else {                             // W_proj [1024][1024] -> [1024][1024]
    bid -= 3072;
    src = Wp; dst = Wtp; R = DIM; C = DIM;
    bx = bid & 31; by = bid >> 5;
  }
  __shared__ float t[32][33];
  const int r0 = by * 32, c0 = bx * 32;
  const int tx = tid & 31, ty = tid >> 5;
#pragma unroll
  for (int i = 0; i < 4; ++i)
    t[ty + i * 8][tx] = src[(size_t)(r0 + ty + i * 8) * C + c0 + tx];
  __syncthreads();
#pragma unroll
  for (int i = 0; i < 4; ++i)
    dst[(size_t)(c0 + ty + i * 8) * R + r0 + tx] = f2bf(t[tx][ty + i * 8]);
}

// ---------------------------------------------------------------------------
// Kernel 1: qkv = x_bf @ Wt_qkv^T + b. 128x128 tile, BK=64 (16 k-steps:
// half the barrier drains of BK=32; 32 KB LDS keeps >=3 blocks/CU).
// Outputs: Q [bh][t][d] (pre-scaled), Kf/Vf fragment-linear (round 8).
// Operand-swap epilogue (round 9): Q/K transposed, V normal.
// ---------------------------------------------------------------------------
__global__ __launch_bounds__(256) void qkv_mfma(
    const unsigned short* __restrict__ Ax,   // [4096][1024] bf16
    const unsigned short* __restrict__ Bt,   // [3072][1024] bf16 (W^T)
    const float* __restrict__ bias,
    unsigned short* __restrict__ Qb, unsigned short* __restrict__ Kf,
    unsigned short* __restrict__ Vf) {
  const int row0 = blockIdx.y * 128;
  const int col0 = blockIdx.x * 128;
  const int tid  = threadIdx.x;
  const int lane = tid & 63;
  const int wave = tid >> 6;
  const int col  = lane & 15;
  const int quad = lane >> 4;
  const int wm = wave >> 1, wn = wave & 1;

  __shared__ unsigned short As[128 * 64];    // 16 KB
  __shared__ unsigned short Bs[128 * 64];    // 16 KB

  const int which = col0 >> 10;        // 0=Q 1=K 2=V, block-uniform

  f32x4 acc[4][4];
#pragma unroll
  for (int i = 0; i < 4; ++i)
#pragma unroll
    for (int j = 0; j < 4; ++j) acc[i][j] = (f32x4){0.f, 0.f, 0.f, 0.f};

  if (which == 2) {                    // V: normal orientation
    for (int k0 = 0; k0 < DIM; k0 += 64) {
      __syncthreads();
#pragma unroll
      for (int it = 0; it < 4; ++it) {
        int c = tid + it * 256;        // 0..1023
        int r = c >> 3, o8 = (c & 7) * 8;
        async_copy16(Ax + (size_t)(row0 + r) * DIM + k0 + o8, &As[c * 8]);
        async_copy16(Bt + (size_t)(col0 + r) * DIM + k0 + o8, &Bs[c * 8]);
      }
      __syncthreads();
#pragma unroll
      for (int ks = 0; ks < 2; ++ks) {
        bfrag a[4], b[4];
#pragma unroll
        for (int i = 0; i < 4; ++i)
          a[i] = *(const bfrag*)&As[(wm * 64 + i * 16 + col) * 64 + ks * 32 +
                                    quad * 8];
#pragma unroll
        for (int j = 0; j < 4; ++j)
          b[j] = *(const bfrag*)&Bs[(wn * 64 + j * 16 + col) * 64 + ks * 32 +
                                    quad * 8];
#pragma unroll
        for (int i = 0; i < 4; ++i)
#pragma unroll
          for (int j = 0; j < 4; ++j)
            acc[i][j] = __builtin_amdgcn_mfma_f32_16x16x32_bf16(
                a[i], b[j], acc[i][j], 0, 0, 0);
      }
    }
  } else {                             // Q/K: transposed (operand swap)
    for (int k0 = 0; k0 < DIM; k0 += 64) {
      __syncthreads();
#pragma unroll
      for (int it = 0; it < 4; ++it) {
        int c = tid + it * 256;
        int r = c >> 3, o8 = (c & 7) * 8;
        async_copy16(Ax + (size_t)(row0 + r) * DIM + k0 + o8, &As[c * 8]);
        async_copy16(Bt + (size_t)(col0 + r) * DIM + k0 + o8, &Bs[c * 8]);
      }
      __syncthreads();
#pragma unroll
      for (int ks = 0; ks < 2; ++ks) {
        bfrag a[4], b[4];
#pragma unroll
        for (int i = 0; i < 4; ++i)
          a[i] = *(const bfrag*)&As[(wm * 64 + i * 16 + col) * 64 + ks * 32 +
                                    quad * 8];
#pragma unroll
        for (int j = 0; j < 4; ++j)
          b[j] = *(const bfrag*)&Bs[(wn * 64 + j * 16 + col) * 64 + ks * 32 +
                                    quad * 8];
#pragma unroll
        for (int i = 0; i < 4; ++i)
#pragma unroll
          for (int j = 0; j < 4; ++j)
            acc[i][j] = __builtin_amdgcn_mfma_f32_16x16x32_bf16(
                b[j], a[i], acc[i][j], 0, 0, 0);
      }
    }
  }

  const int bb = row0 >> 11;                        // block-uniform batch
  const int hq = ((col0 + wn * 64) & 1023) >> 6;    // wave-uniform head
  const int bh = bb * NH + hq;
  const int t  = ((row0 + wm * 64) & 2047) >> 6;    // wave-uniform tile

  if (which == 2) {
    float bj[4];
#pragma unroll
    for (int j = 0; j < 4; ++j) bj[j] = bias[col0 + wn * 64 + j * 16 + col];
#pragma unroll
    for (int i = 0; i < 4; ++i) {
      const size_t base_i =
          (((size_t)bh * 32 + t) * 8) * 512 + (size_t)((i >> 1) & 1) * 512 +
          (size_t)(quad & 1) * 4;
      const int rowsub = (i * 2 + (quad >> 1)) & 3;
#pragma unroll
      for (int j = 0; j < 4; ++j) {
        ushort4 pk = {f2bf(acc[i][j][0] + bj[j]), f2bf(acc[i][j][1] + bj[j]),
                      f2bf(acc[i][j][2] + bj[j]), f2bf(acc[i][j][3] + bj[j])};
        const size_t idx =
            base_i + (size_t)j * 1024 + (size_t)(rowsub * 16 + col) * 8;
        *(ushort4*)&Vf[idx] = pk;
      }
    }
  } else {
    const int ttl = row0 + wm * 64;
#pragma unroll
    for (int j = 0; j < 4; ++j) {
      const float4 b4 =
          *(const float4*)&bias[col0 + wn * 64 + j * 16 + quad * 4];
#pragma unroll
      for (int i = 0; i < 4; ++i) {
        f32x4 v = acc[i][j];
        v[0] += b4.x; v[1] += b4.y; v[2] += b4.z; v[3] += b4.w;
        if (which == 0) {
          v[0] *= QSCALE; v[1] *= QSCALE; v[2] *= QSCALE; v[3] *= QSCALE;
          ushort4 pk = {f2bf(v[0]), f2bf(v[1]), f2bf(v[2]), f2bf(v[3])};
          const int tt = (ttl + i * 16 + col) & 2047;
          *(ushort4*)&Qb[((size_t)bh * SEQ + tt) * HD + j * 16 + quad * 4] = pk;
        } else {
          ushort4 pk = {f2bf(v[0]), f2bf(v[1]), f2bf(v[2]), f2bf(v[3])};
          const int kg = ((col >> 2) & 1) | ((i >> 1) << 1);
          const int ck = ((i * 2 + (col >> 3)) & 3) * 4 + (col & 3);
          const size_t idx =
              ((((size_t)bh * 32 + t) * 4 + kg) * 2 + (j >> 1)) * 512 +
              (size_t)(((j & 1) * 2 + (quad >> 1)) * 16 + ck) * 8 +
              (quad & 1) * 4;
          *(ushort4*)&Kf[idx] = pk;
        }
      }
    }
  }
}

// ---------------------------------------------------------------------------
// Kernel 2: MFMA flash attention, max-free softmax (unchanged from round 10).
// ---------------------------------------------------------------------------
__global__ __launch_bounds__(256) void flash_mfma(
    const unsigned short* __restrict__ Qb, const unsigned short* __restrict__ Kf,
    const unsigned short* __restrict__ Vf, unsigned short* __restrict__ Abf) {
  const int blk  = blockIdx.x;         // 0..2047
  const int bh   = blk & 31;           // same head -> same XCD (32 % 8 == 0)
  const int qc   = 63 - (blk >> 5);    // 32-row q chunk, biggest first
  const int q0   = qc * 32;
  const int tid  = threadIdx.x;
  const int lane = tid & 63;
  const int wave = tid >> 6;
  const int col  = lane & 15;
  const int quad = lane >> 4;

  const int ntiles = (qc >> 1) + 1;
  const int nw     = (ntiles < 4) ? ntiles : 4;

  __shared__ float Om[4][64][33];
  __shared__ float Ml[4][4][32];

  bfrag qb[2][2];
  {
    const unsigned short* qp = Qb + ((size_t)bh * SEQ + q0 + col) * HD;
    qb[0][0] = *(const bfrag*)(qp + quad * 8);
    qb[0][1] = *(const bfrag*)(qp + 32 + quad * 8);
    qb[1][0] = *(const bfrag*)(qp + 16 * HD + quad * 8);
    qb[1][1] = *(const bfrag*)(qp + 16 * HD + 32 + quad * 8);
  }

  const unsigned short* kfb = Kf + (size_t)bh * SEQ * HD + lane * 8;
  const unsigned short* vfb = Vf + (size_t)bh * SEQ * HD + lane * 8;

  f32x4 o[2][4];
#pragma unroll
  for (int qf = 0; qf < 2; ++qf)
#pragma unroll
    for (int n = 0; n < 4; ++n) o[qf][n] = (f32x4){0.f, 0.f, 0.f, 0.f};
  float l_p[2] = {0.f, 0.f};

  auto loadK = [&](int t, bfrag (&kd)[4][2]) {
    const unsigned short* p = kfb + (size_t)t * 4096;
#pragma unroll
    for (int kg = 0; kg < 4; ++kg) {
      kd[kg][0] = *(const bfrag*)(p + (kg * 2 + 0) * 512);
      kd[kg][1] = *(const bfrag*)(p + (kg * 2 + 1) * 512);
    }
  };

  auto proc = [&](int t, bfrag (&kc)[4][2], bfrag (&kn)[4][2]) {
    const int k0 = t * 64;
    bfrag va[4][2];
    {
      const unsigned short* p = vfb + (size_t)t * 4096;
#pragma unroll
      for (int n = 0; n < 4; ++n) {
        va[n][0] = *(const bfrag*)(p + (n * 2 + 0) * 512);
        va[n][1] = *(const bfrag*)(p + (n * 2 + 1) * 512);
      }
    }
    loadK((t + 4 < ntiles) ? t + 4 : t, kn);

    const bool last = (t == ntiles - 1);
#pragma unroll
    for (int qf = 0; qf < 2; ++qf) {
      f32x4 s[4];
#pragma unroll
      for (int kg = 0; kg < 4; ++kg) {
        f32x4 c = (f32x4){0.f, 0.f, 0.f, 0.f};
        c = __builtin_amdgcn_mfma_f32_16x16x32_bf16(kc[kg][0], qb[qf][0], c,
                                                    0, 0, 0);
        c = __builtin_amdgcn_mfma_f32_16x16x32_bf16(kc[kg][1], qb[qf][1], c,
                                                    0, 0, 0);
        s[kg] = c;
      }
      if (last) {
        const int q = q0 + qf * 16 + col;
#pragma unroll
        for (int kg = 0; kg < 4; ++kg)
#pragma unroll
          for (int r = 0; r < 4; ++r) {
            int key = k0 + quad * 8 + (kg & 1) * 4 + r + (kg & 2) * 16;
            if (key > q) s[kg][r] = -3.0e38f;
          }
      }
      float lsum = 0.f;
#pragma unroll
      for (int kg = 0; kg < 4; ++kg)
#pragma unroll
        for (int r = 0; r < 4; ++r) {
          float p = EXP2F(s[kg][r]);
          s[kg][r] = p;
          lsum += p;
        }
      l_p[qf] += lsum;

      bfrag pa0, pa1;
#pragma unroll
      for (int r = 0; r < 4; ++r) {
        pa0[r]     = (__bf16)s[0][r];
        pa0[4 + r] = (__bf16)s[1][r];
        pa1[r]     = (__bf16)s[2][r];
        pa1[4 + r] = (__bf16)s[3][r];
      }
#pragma unroll
      for (int n = 0; n < 4; ++n) {
        o[qf][n] = __builtin_amdgcn_mfma_f32_16x16x32_bf16(va[n][0], pa0,
                                                           o[qf][n], 0, 0, 0);
        o[qf][n] = __builtin_amdgcn_mfma_f32_16x16x32_bf16(va[n][1], pa1,
                                                           o[qf][n], 0, 0, 0);
      }
    }
  };

  if (wave < ntiles) {
    bfrag kaA[4][2], kaB[4][2];
    loadK(wave, kaA);
    for (int t = wave; t < ntiles; t += 8) {
      proc(t, kaA, kaB);
      if (t + 4 < ntiles) proc(t + 4, kaB, kaA);
    }
  }

  if (wave < nw) {
#pragma unroll
    for (int qf = 0; qf < 2; ++qf)
#pragma unroll
      for (int n = 0; n < 4; ++n)
#pragma unroll
        for (int r = 0; r < 4; ++r)
          Om[wave][n * 16 + quad * 4 + r][qf * 16 + col] = o[qf][n][r];
#pragma unroll
    for (int qf = 0; qf < 2; ++qf)
      Ml[wave][quad][qf * 16 + col] = l_p[qf];
  }
  __syncthreads();

  {
    const int q  = tid & 31;
    const int d0 = (tid >> 5) * 8;
    float lt = 0.f;
    for (int w = 0; w < nw; ++w)
#pragma unroll
      for (int qd = 0; qd < 4; ++qd) lt += Ml[w][qd][q];
    float acc[8] = {};
    for (int w = 0; w < nw; ++w)
#pragma unroll
      for (int j = 0; j < 8; ++j) acc[j] += Om[w][d0 + j][q];
    const float inv = 1.0f / lt;
    const int b = bh >> 4, h = bh & 15;
    unsigned short* dst = Abf + ((size_t)b * SEQ + q0 + q) * DIM + h * HD + d0;
    ushort4 p1 = {f2bf(acc[0] * inv), f2bf(acc[1] * inv),
                  f2bf(acc[2] * inv), f2bf(acc[3] * inv)};
    ushort4 p2 = {f2bf(acc[4] * inv), f2bf(acc[5] * inv),
                  f2bf(acc[6] * inv), f2bf(acc[7] * inv)};
    *(ushort4*)dst = p1;
    *(ushort4*)(dst + 4) = p2;
  }
}

// ---------------------------------------------------------------------------
// Kernel 3: out = Abf @ Wt_proj^T + b_proj (fp32). Tile 128M x 64N, BK=64:
// 512 blocks (2/CU, was 1/CU at 128x128) + half the barriers. Wave w owns
// rows wm*32..+31 x all 64 cols: acc[2][4]. Transposed accumulation ->
// float4 stores, fully coalesced.
// ---------------------------------------------------------------------------
__global__ __launch_bounds__(256) void proj_mfma(
    const unsigned short* __restrict__ Ax,
    const unsigned short* __restrict__ Bt,
    const float* __restrict__ bias, float* __restrict__ out) {
  const int row0 = blockIdx.y * 128;
  const int col0 = blockIdx.x * 64;
  const int tid  = threadIdx.x;
  const int lane = tid & 63;
  const int wave = tid >> 6;           // wm = wave: rows wave*32..+31
  const int col  = lane & 15;
  const int quad = lane >> 4;

  __shared__ unsigned short As[128 * 64];    // 16 KB
  __shared__ unsigned short Bs[64 * 64];     // 8 KB

  f32x4 acc[2][4];
#pragma unroll
  for (int i = 0; i < 2; ++i)
#pragma unroll
    for (int j = 0; j < 4; ++j) acc[i][j] = (f32x4){0.f, 0.f, 0.f, 0.f};

  for (int k0 = 0; k0 < DIM; k0 += 64) {
    __syncthreads();
#pragma unroll
    for (int it = 0; it < 4; ++it) {   // A: 1024 chunks
      int c = tid + it * 256;
      int r = c >> 3, o8 = (c & 7) * 8;
      async_copy16(Ax + (size_t)(row0 + r) * DIM + k0 + o8, &As[c * 8]);
    }
#pragma unroll
    for (int it = 0; it < 2; ++it) {   // B: 512 chunks
      int c = tid + it * 256;
      int r = c >> 3, o8 = (c & 7) * 8;
      async_copy16(Bt + (size_t)(col0 + r) * DIM + k0 + o8, &Bs[c * 8]);
    }
    __syncthreads();

#pragma unroll
    for (int ks = 0; ks < 2; ++ks) {
      bfrag a[2], b[4];
#pragma unroll
      for (int i = 0; i < 2; ++i)
        a[i] = *(const bfrag*)&As[(wave * 32 + i * 16 + col) * 64 + ks * 32 +
                                  quad * 8];
#pragma unroll
      for (int j = 0; j < 4; ++j)
        b[j] = *(const bfrag*)&Bs[(j * 16 + col) * 64 + ks * 32 + quad * 8];
#pragma unroll
      for (int i = 0; i < 2; ++i)
#pragma unroll
        for (int j = 0; j < 4; ++j)
          acc[i][j] = __builtin_amdgcn_mfma_f32_16x16x32_bf16(
              b[j], a[i], acc[i][j], 0, 0, 0);   // transposed
    }
  }

  // tt = row0 + wave*32 + i*16 + col, cout = col0 + j*16 + quad*4 + r
#pragma unroll
  for (int j = 0; j < 4; ++j) {
    const int c4 = col0 + j * 16 + quad * 4;
    const float4 b4 = *(const float4*)&bias[c4];
#pragma unroll
    for (int i = 0; i < 2; ++i) {
      const int tt = row0 + wave * 32 + i * 16 + col;
      float4 v = {acc[i][j][0] + b4.x, acc[i][j][1] + b4.y,
                  acc[i][j][2] + b4.z, acc[i][j][3] + b4.w};
      *(float4*)&out[(size_t)tt * DIM + c4] = v;
    }
  }
}

// ---------------------------------------------------------------------------
extern "C" void kernel_launch(void* const* d_in, const int* in_sizes, int n_in,
                              void* d_out, int out_size, void* d_ws, size_t ws_size,
                              hipStream_t stream) {
  const float* x      = (const float*)d_in[0];
  const float* W_qkv  = (const float*)d_in[1];
  const float* b_qkv  = (const float*)d_in[2];
  const float* W_proj = (const float*)d_in[3];
  const float* b_proj = (const float*)d_in[4];
  float* out = (float*)d_out;

  const size_t qkv_elems = (size_t)BATCH * NH * SEQ * HD;  // 4M
  unsigned short* Qb  = (unsigned short*)d_ws;
  unsigned short* Kf  = Qb + qkv_elems;
  unsigned short* Vf  = Kf + qkv_elems;
  unsigned short* Abf = Vf + qkv_elems;                    // [B,T,C] bf16
  unsigned short* xb  = Abf + qkv_elems;                   // [4096][1024]
  unsigned short* Wtq = xb + (size_t)NROWS * DIM;          // [3072][1024]
  unsigned short* Wtp = Wtq + (size_t)3072 * DIM;          // [1024][1024]

  cvt_all<<<dim3(4096 + 3072 + 1024), 256, 0, stream>>>(x, xb, W_qkv, Wtq,
                                                        W_proj, Wtp);

  qkv_mfma<<<dim3(3072 / 128, NROWS / 128), 256, 0, stream>>>(
      xb, Wtq, b_qkv, Qb, Kf, Vf);

  flash_mfma<<<dim3(BATCH * NH * (SEQ / 32)), 256, 0, stream>>>(Qb, Kf, Vf,
                                                                Abf);

  proj_mfma<<<dim3(DIM / 64, NROWS / 128), 256, 0, stream>>>(
      Abf, Wtp, b_proj, out);
}

// Round 12
// 171.783 us; speedup vs baseline: 1.0980x; 1.0980x over previous
//
#include <hip/hip_runtime.h>
#include <hip/hip_bf16.h>
#include <cstddef>
#include <cstdint>

#define DIM   1024
#define NH    16
#define HD    64
#define BATCH 2
#define SEQ   2048
#define NROWS (BATCH * SEQ)   // 4096
#define QSCALE 0.1803368801111204f   // 0.125 * log2(e): softmax in exp2 domain

typedef __bf16 bfrag  __attribute__((ext_vector_type(8)));
typedef float  f32x4  __attribute__((ext_vector_type(4)));

#if __has_builtin(__builtin_amdgcn_exp2f)
#define EXP2F(x) __builtin_amdgcn_exp2f(x)
#else
#define EXP2F(x) exp2f(x)
#endif

__device__ __forceinline__ unsigned short f2bf(float f) {
  union { float f; uint32_t u; } v; v.f = f;
  uint32_t r = (v.u + 0x7FFF + ((v.u >> 16) & 1)) >> 16;
  return (unsigned short)r;
}

__device__ __forceinline__ void async_copy16(const unsigned short* g,
                                             unsigned short* l) {
  __builtin_amdgcn_global_load_lds(
      (const __attribute__((address_space(1))) unsigned int*)g,
      (__attribute__((address_space(3))) unsigned int*)l, 16, 0, 0);
}

// ---------------------------------------------------------------------------
// Prep (single launch): section 0 = x fp32->bf16; sections 1/2 = W_qkv /
// W_proj transpose-convert. Branch is block-uniform (on blockIdx).
// ---------------------------------------------------------------------------
__global__ __launch_bounds__(256) void cvt_all(
    const float* __restrict__ x, unsigned short* __restrict__ xb,
    const float* __restrict__ Wq, unsigned short* __restrict__ Wtq,
    const float* __restrict__ Wp, unsigned short* __restrict__ Wtp) {
  int bid = blockIdx.x;
  const int tid = threadIdx.x;
  if (bid < 4096) {                    // cvt_x: 1024 floats per block
    int i = (bid * 256 + tid) * 4;
    float4 v = *(const float4*)(x + i);
    ushort4 p = {f2bf(v.x), f2bf(v.y), f2bf(v.z), f2bf(v.w)};
    *(ushort4*)(xb + i) = p;
    return;
  }
  bid -= 4096;
  const float* src;
  unsigned short* dst;
  int R, C, bx, by;
  if (bid < 3072) {                    // W_qkv [1024][3072] -> [3072][1024]
    src = Wq; dst = Wtq; R = DIM; C = 3072;
    bx = bid % 96; by = bid / 96;
  } else {                             // W_proj [1024][1024] -> [1024][1024]
    bid -= 3072;
    src = Wp; dst = Wtp; R = DIM; C = DIM;
    bx = bid & 31; by = bid >> 5;
  }
  __shared__ float t[32][33];
  const int r0 = by * 32, c0 = bx * 32;
  const int tx = tid & 31, ty = tid >> 5;
#pragma unroll
  for (int i = 0; i < 4; ++i)
    t[ty + i * 8][tx] = src[(size_t)(r0 + ty + i * 8) * C + c0 + tx];
  __syncthreads();
#pragma unroll
  for (int i = 0; i < 4; ++i)
    dst[(size_t)(c0 + ty + i * 8) * R + r0 + tx] = f2bf(t[tx][ty + i * 8]);
}

// ---------------------------------------------------------------------------
// Kernel 1: qkv = x_bf @ Wt_qkv^T + b. 128x128 tile, BK=32 (round-10 config:
// BK=64 regressed -- occupancy drop + 3x bank conflicts from 128B LDS
// stride; this family is occupancy/conflict-limited, not barrier-limited).
// Outputs: Q [bh][t][d] (pre-scaled), Kf/Vf fragment-linear (round 8).
// Operand-swap epilogue (round 9): Q/K transposed, V normal.
// ---------------------------------------------------------------------------
__global__ __launch_bounds__(256) void qkv_mfma(
    const unsigned short* __restrict__ Ax,   // [4096][1024] bf16
    const unsigned short* __restrict__ Bt,   // [3072][1024] bf16 (W^T)
    const float* __restrict__ bias,
    unsigned short* __restrict__ Qb, unsigned short* __restrict__ Kf,
    unsigned short* __restrict__ Vf) {
  const int row0 = blockIdx.y * 128;
  const int col0 = blockIdx.x * 128;
  const int tid  = threadIdx.x;
  const int lane = tid & 63;
  const int wave = tid >> 6;
  const int col  = lane & 15;
  const int quad = lane >> 4;
  const int wm = wave >> 1, wn = wave & 1;

  __shared__ unsigned short As[128 * 32];
  __shared__ unsigned short Bs[128 * 32];

  const int which = col0 >> 10;        // 0=Q 1=K 2=V, block-uniform

  f32x4 acc[4][4];
#pragma unroll
  for (int i = 0; i < 4; ++i)
#pragma unroll
    for (int j = 0; j < 4; ++j) acc[i][j] = (f32x4){0.f, 0.f, 0.f, 0.f};

  if (which == 2) {                    // V: normal orientation
    for (int k0 = 0; k0 < DIM; k0 += 32) {
      __syncthreads();
#pragma unroll
      for (int it = 0; it < 2; ++it) {
        int c = tid + it * 256;
        int r = c >> 2, o8 = (c & 3) * 8;
        async_copy16(Ax + (size_t)(row0 + r) * DIM + k0 + o8, &As[c * 8]);
        async_copy16(Bt + (size_t)(col0 + r) * DIM + k0 + o8, &Bs[c * 8]);
      }
      __syncthreads();
      bfrag a[4], b[4];
#pragma unroll
      for (int i = 0; i < 4; ++i)
        a[i] = *(const bfrag*)&As[(wm * 64 + i * 16 + col) * 32 + quad * 8];
#pragma unroll
      for (int j = 0; j < 4; ++j)
        b[j] = *(const bfrag*)&Bs[(wn * 64 + j * 16 + col) * 32 + quad * 8];
#pragma unroll
      for (int i = 0; i < 4; ++i)
#pragma unroll
        for (int j = 0; j < 4; ++j)
          acc[i][j] = __builtin_amdgcn_mfma_f32_16x16x32_bf16(
              a[i], b[j], acc[i][j], 0, 0, 0);
    }
  } else {                             // Q/K: transposed (operand swap)
    for (int k0 = 0; k0 < DIM; k0 += 32) {
      __syncthreads();
#pragma unroll
      for (int it = 0; it < 2; ++it) {
        int c = tid + it * 256;
        int r = c >> 2, o8 = (c & 3) * 8;
        async_copy16(Ax + (size_t)(row0 + r) * DIM + k0 + o8, &As[c * 8]);
        async_copy16(Bt + (size_t)(col0 + r) * DIM + k0 + o8, &Bs[c * 8]);
      }
      __syncthreads();
      bfrag a[4], b[4];
#pragma unroll
      for (int i = 0; i < 4; ++i)
        a[i] = *(const bfrag*)&As[(wm * 64 + i * 16 + col) * 32 + quad * 8];
#pragma unroll
      for (int j = 0; j < 4; ++j)
        b[j] = *(const bfrag*)&Bs[(wn * 64 + j * 16 + col) * 32 + quad * 8];
#pragma unroll
      for (int i = 0; i < 4; ++i)
#pragma unroll
        for (int j = 0; j < 4; ++j)
          acc[i][j] = __builtin_amdgcn_mfma_f32_16x16x32_bf16(
              b[j], a[i], acc[i][j], 0, 0, 0);
    }
  }

  const int bb = row0 >> 11;                        // block-uniform batch
  const int hq = ((col0 + wn * 64) & 1023) >> 6;    // wave-uniform head
  const int bh = bb * NH + hq;
  const int t  = ((row0 + wm * 64) & 2047) >> 6;    // wave-uniform tile

  if (which == 2) {
    float bj[4];
#pragma unroll
    for (int j = 0; j < 4; ++j) bj[j] = bias[col0 + wn * 64 + j * 16 + col];
#pragma unroll
    for (int i = 0; i < 4; ++i) {
      const size_t base_i =
          (((size_t)bh * 32 + t) * 8) * 512 + (size_t)((i >> 1) & 1) * 512 +
          (size_t)(quad & 1) * 4;
      const int rowsub = (i * 2 + (quad >> 1)) & 3;
#pragma unroll
      for (int j = 0; j < 4; ++j) {
        ushort4 pk = {f2bf(acc[i][j][0] + bj[j]), f2bf(acc[i][j][1] + bj[j]),
                      f2bf(acc[i][j][2] + bj[j]), f2bf(acc[i][j][3] + bj[j])};
        const size_t idx =
            base_i + (size_t)j * 1024 + (size_t)(rowsub * 16 + col) * 8;
        *(ushort4*)&Vf[idx] = pk;
      }
    }
  } else {
    const int ttl = row0 + wm * 64;
#pragma unroll
    for (int j = 0; j < 4; ++j) {
      const float4 b4 =
          *(const float4*)&bias[col0 + wn * 64 + j * 16 + quad * 4];
#pragma unroll
      for (int i = 0; i < 4; ++i) {
        f32x4 v = acc[i][j];
        v[0] += b4.x; v[1] += b4.y; v[2] += b4.z; v[3] += b4.w;
        if (which == 0) {
          v[0] *= QSCALE; v[1] *= QSCALE; v[2] *= QSCALE; v[3] *= QSCALE;
          ushort4 pk = {f2bf(v[0]), f2bf(v[1]), f2bf(v[2]), f2bf(v[3])};
          const int tt = (ttl + i * 16 + col) & 2047;
          *(ushort4*)&Qb[((size_t)bh * SEQ + tt) * HD + j * 16 + quad * 4] = pk;
        } else {
          ushort4 pk = {f2bf(v[0]), f2bf(v[1]), f2bf(v[2]), f2bf(v[3])};
          const int kg = ((col >> 2) & 1) | ((i >> 1) << 1);
          const int ck = ((i * 2 + (col >> 3)) & 3) * 4 + (col & 3);
          const size_t idx =
              ((((size_t)bh * 32 + t) * 4 + kg) * 2 + (j >> 1)) * 512 +
              (size_t)(((j & 1) * 2 + (quad >> 1)) * 16 + ck) * 8 +
              (quad & 1) * 4;
          *(ushort4*)&Kf[idx] = pk;
        }
      }
    }
  }
}

// ---------------------------------------------------------------------------
// Kernel 2: MFMA flash attention, max-free softmax (round-10, unchanged).
// ---------------------------------------------------------------------------
__global__ __launch_bounds__(256) void flash_mfma(
    const unsigned short* __restrict__ Qb, const unsigned short* __restrict__ Kf,
    const unsigned short* __restrict__ Vf, unsigned short* __restrict__ Abf) {
  const int blk  = blockIdx.x;         // 0..2047
  const int bh   = blk & 31;           // same head -> same XCD (32 % 8 == 0)
  const int qc   = 63 - (blk >> 5);    // 32-row q chunk, biggest first
  const int q0   = qc * 32;
  const int tid  = threadIdx.x;
  const int lane = tid & 63;
  const int wave = tid >> 6;
  const int col  = lane & 15;
  const int quad = lane >> 4;

  const int ntiles = (qc >> 1) + 1;
  const int nw     = (ntiles < 4) ? ntiles : 4;

  __shared__ float Om[4][64][33];
  __shared__ float Ml[4][4][32];

  bfrag qb[2][2];
  {
    const unsigned short* qp = Qb + ((size_t)bh * SEQ + q0 + col) * HD;
    qb[0][0] = *(const bfrag*)(qp + quad * 8);
    qb[0][1] = *(const bfrag*)(qp + 32 + quad * 8);
    qb[1][0] = *(const bfrag*)(qp + 16 * HD + quad * 8);
    qb[1][1] = *(const bfrag*)(qp + 16 * HD + 32 + quad * 8);
  }

  const unsigned short* kfb = Kf + (size_t)bh * SEQ * HD + lane * 8;
  const unsigned short* vfb = Vf + (size_t)bh * SEQ * HD + lane * 8;

  f32x4 o[2][4];
#pragma unroll
  for (int qf = 0; qf < 2; ++qf)
#pragma unroll
    for (int n = 0; n < 4; ++n) o[qf][n] = (f32x4){0.f, 0.f, 0.f, 0.f};
  float l_p[2] = {0.f, 0.f};

  auto loadK = [&](int t, bfrag (&kd)[4][2]) {
    const unsigned short* p = kfb + (size_t)t * 4096;
#pragma unroll
    for (int kg = 0; kg < 4; ++kg) {
      kd[kg][0] = *(const bfrag*)(p + (kg * 2 + 0) * 512);
      kd[kg][1] = *(const bfrag*)(p + (kg * 2 + 1) * 512);
    }
  };

  auto proc = [&](int t, bfrag (&kc)[4][2], bfrag (&kn)[4][2]) {
    const int k0 = t * 64;
    bfrag va[4][2];
    {
      const unsigned short* p = vfb + (size_t)t * 4096;
#pragma unroll
      for (int n = 0; n < 4; ++n) {
        va[n][0] = *(const bfrag*)(p + (n * 2 + 0) * 512);
        va[n][1] = *(const bfrag*)(p + (n * 2 + 1) * 512);
      }
    }
    loadK((t + 4 < ntiles) ? t + 4 : t, kn);

    const bool last = (t == ntiles - 1);
#pragma unroll
    for (int qf = 0; qf < 2; ++qf) {
      f32x4 s[4];
#pragma unroll
      for (int kg = 0; kg < 4; ++kg) {
        f32x4 c = (f32x4){0.f, 0.f, 0.f, 0.f};
        c = __builtin_amdgcn_mfma_f32_16x16x32_bf16(kc[kg][0], qb[qf][0], c,
                                                    0, 0, 0);
        c = __builtin_amdgcn_mfma_f32_16x16x32_bf16(kc[kg][1], qb[qf][1], c,
                                                    0, 0, 0);
        s[kg] = c;
      }
      if (last) {
        const int q = q0 + qf * 16 + col;
#pragma unroll
        for (int kg = 0; kg < 4; ++kg)
#pragma unroll
          for (int r = 0; r < 4; ++r) {
            int key = k0 + quad * 8 + (kg & 1) * 4 + r + (kg & 2) * 16;
            if (key > q) s[kg][r] = -3.0e38f;
          }
      }
      float lsum = 0.f;
#pragma unroll
      for (int kg = 0; kg < 4; ++kg)
#pragma unroll
        for (int r = 0; r < 4; ++r) {
          float p = EXP2F(s[kg][r]);
          s[kg][r] = p;
          lsum += p;
        }
      l_p[qf] += lsum;

      bfrag pa0, pa1;
#pragma unroll
      for (int r = 0; r < 4; ++r) {
        pa0[r]     = (__bf16)s[0][r];
        pa0[4 + r] = (__bf16)s[1][r];
        pa1[r]     = (__bf16)s[2][r];
        pa1[4 + r] = (__bf16)s[3][r];
      }
#pragma unroll
      for (int n = 0; n < 4; ++n) {
        o[qf][n] = __builtin_amdgcn_mfma_f32_16x16x32_bf16(va[n][0], pa0,
                                                           o[qf][n], 0, 0, 0);
        o[qf][n] = __builtin_amdgcn_mfma_f32_16x16x32_bf16(va[n][1], pa1,
                                                           o[qf][n], 0, 0, 0);
      }
    }
  };

  if (wave < ntiles) {
    bfrag kaA[4][2], kaB[4][2];
    loadK(wave, kaA);
    for (int t = wave; t < ntiles; t += 8) {
      proc(t, kaA, kaB);
      if (t + 4 < ntiles) proc(t + 4, kaB, kaA);
    }
  }

  if (wave < nw) {
#pragma unroll
    for (int qf = 0; qf < 2; ++qf)
#pragma unroll
      for (int n = 0; n < 4; ++n)
#pragma unroll
        for (int r = 0; r < 4; ++r)
          Om[wave][n * 16 + quad * 4 + r][qf * 16 + col] = o[qf][n][r];
#pragma unroll
    for (int qf = 0; qf < 2; ++qf)
      Ml[wave][quad][qf * 16 + col] = l_p[qf];
  }
  __syncthreads();

  {
    const int q  = tid & 31;
    const int d0 = (tid >> 5) * 8;
    float lt = 0.f;
    for (int w = 0; w < nw; ++w)
#pragma unroll
      for (int qd = 0; qd < 4; ++qd) lt += Ml[w][qd][q];
    float acc[8] = {};
    for (int w = 0; w < nw; ++w)
#pragma unroll
      for (int j = 0; j < 8; ++j) acc[j] += Om[w][d0 + j][q];
    const float inv = 1.0f / lt;
    const int b = bh >> 4, h = bh & 15;
    unsigned short* dst = Abf + ((size_t)b * SEQ + q0 + q) * DIM + h * HD + d0;
    ushort4 p1 = {f2bf(acc[0] * inv), f2bf(acc[1] * inv),
                  f2bf(acc[2] * inv), f2bf(acc[3] * inv)};
    ushort4 p2 = {f2bf(acc[4] * inv), f2bf(acc[5] * inv),
                  f2bf(acc[6] * inv), f2bf(acc[7] * inv)};
    *(ushort4*)dst = p1;
    *(ushort4*)(dst + 4) = p2;
  }
}

// ---------------------------------------------------------------------------
// Kernel 3: out = Abf @ Wt_proj^T + b_proj (fp32). Tile 128M x 64N, BK=32:
// 512 blocks (2/CU) and 64B LDS stride (conflict-free fragment reads).
// Transposed accumulation -> float4 stores, fully coalesced.
// ---------------------------------------------------------------------------
__global__ __launch_bounds__(256) void proj_mfma(
    const unsigned short* __restrict__ Ax,
    const unsigned short* __restrict__ Bt,
    const float* __restrict__ bias, float* __restrict__ out) {
  const int row0 = blockIdx.y * 128;
  const int col0 = blockIdx.x * 64;
  const int tid  = threadIdx.x;
  const int lane = tid & 63;
  const int wave = tid >> 6;           // rows wave*32..+31
  const int col  = lane & 15;
  const int quad = lane >> 4;

  __shared__ unsigned short As[128 * 32];    // 8 KB
  __shared__ unsigned short Bs[64 * 32];     // 4 KB

  f32x4 acc[2][4];
#pragma unroll
  for (int i = 0; i < 2; ++i)
#pragma unroll
    for (int j = 0; j < 4; ++j) acc[i][j] = (f32x4){0.f, 0.f, 0.f, 0.f};

  for (int k0 = 0; k0 < DIM; k0 += 32) {
    __syncthreads();
#pragma unroll
    for (int it = 0; it < 2; ++it) {   // A: 512 chunks
      int c = tid + it * 256;
      int r = c >> 2, o8 = (c & 3) * 8;
      async_copy16(Ax + (size_t)(row0 + r) * DIM + k0 + o8, &As[c * 8]);
    }
    {                                  // B: 256 chunks
      int c = tid;
      int r = c >> 2, o8 = (c & 3) * 8;
      async_copy16(Bt + (size_t)(col0 + r) * DIM + k0 + o8, &Bs[c * 8]);
    }
    __syncthreads();

    bfrag a[2], b[4];
#pragma unroll
    for (int i = 0; i < 2; ++i)
      a[i] = *(const bfrag*)&As[(wave * 32 + i * 16 + col) * 32 + quad * 8];
#pragma unroll
    for (int j = 0; j < 4; ++j)
      b[j] = *(const bfrag*)&Bs[(j * 16 + col) * 32 + quad * 8];
#pragma unroll
    for (int i = 0; i < 2; ++i)
#pragma unroll
      for (int j = 0; j < 4; ++j)
        acc[i][j] = __builtin_amdgcn_mfma_f32_16x16x32_bf16(
            b[j], a[i], acc[i][j], 0, 0, 0);   // transposed
  }

  // tt = row0 + wave*32 + i*16 + col, cout = col0 + j*16 + quad*4 + r
#pragma unroll
  for (int j = 0; j < 4; ++j) {
    const int c4 = col0 + j * 16 + quad * 4;
    const float4 b4 = *(const float4*)&bias[c4];
#pragma unroll
    for (int i = 0; i < 2; ++i) {
      const int tt = row0 + wave * 32 + i * 16 + col;
      float4 v = {acc[i][j][0] + b4.x, acc[i][j][1] + b4.y,
                  acc[i][j][2] + b4.z, acc[i][j][3] + b4.w};
      *(float4*)&out[(size_t)tt * DIM + c4] = v;
    }
  }
}

// ---------------------------------------------------------------------------
extern "C" void kernel_launch(void* const* d_in, const int* in_sizes, int n_in,
                              void* d_out, int out_size, void* d_ws, size_t ws_size,
                              hipStream_t stream) {
  const float* x      = (const float*)d_in[0];
  const float* W_qkv  = (const float*)d_in[1];
  const float* b_qkv  = (const float*)d_in[2];
  const float* W_proj = (const float*)d_in[3];
  const float* b_proj = (const float*)d_in[4];
  float* out = (float*)d_out;

  const size_t qkv_elems = (size_t)BATCH * NH * SEQ * HD;  // 4M
  unsigned short* Qb  = (unsigned short*)d_ws;
  unsigned short* Kf  = Qb + qkv_elems;
  unsigned short* Vf  = Kf + qkv_elems;
  unsigned short* Abf = Vf + qkv_elems;                    // [B,T,C] bf16
  unsigned short* xb  = Abf + qkv_elems;                   // [4096][1024]
  unsigned short* Wtq = xb + (size_t)NROWS * DIM;          // [3072][1024]
  unsigned short* Wtp = Wtq + (size_t)3072 * DIM;          // [1024][1024]

  cvt_all<<<dim3(4096 + 3072 + 1024), 256, 0, stream>>>(x, xb, W_qkv, Wtq,
                                                        W_proj, Wtp);

  qkv_mfma<<<dim3(3072 / 128, NROWS / 128), 256, 0, stream>>>(
      xb, Wtq, b_qkv, Qb, Kf, Vf);

  flash_mfma<<<dim3(BATCH * NH * (SEQ / 32)), 256, 0, stream>>>(Qb, Kf, Vf,
                                                                Abf);

  proj_mfma<<<dim3(DIM / 64, NROWS / 128), 256, 0, stream>>>(
      Abf, Wtp, b_proj, out);
}